// Round 1
// baseline (111.532 us; speedup 1.0000x reference)
//
#include <hip/hip_runtime.h>
#include <hip/hip_fp16.h>

// MaddnessMatmul round 6: tree-select encode + 2-tile pipelined blocks.
//   out[m][n] = sum_c luts[c][enc(n,c)][m],  luts[c][k][m] = dot(B[m], P[c][k]).
//
// R5 post-mortem: dur 109.7 = 2x 41.2us d_ws poison fills (harness, 81% HBM
// peak) + encode ~12 + accum ~5 + graph gaps. Encode slack vs its 10.3us BW
// floor traced to (a) serial dependent-LDS sv chain: g -> sv_s[..+g] -> cmp
// -> g is 3 chained ~120cyc LDS reads per codebook at only 2 waves/SIMD, and
// (b) no intra-block load/compute overlap at 1 tile/block. R6:
//  - encode: per-codebook thresholds read as INDEPENDENT broadcast LDS loads
//    (b32/b64/b128, uniform addr = conflict-free), 4-level tree resolved with
//    cndmask selects (identical f32 compares -> bit-identical codes).
//  - encode blocks process 2 tiles (2048 blocks x 128 rows): tile-1 loads
//    issued under tile-0 encode; single-wave blocks so __syncthreads is a
//    cheap waitcnt drain; sv/LUT fixed costs amortized 2x.
//  - accum: codes load issued before LUT staging (latency under LDS fill).

#define NROWS 262144
#define DDIM  64
#define RSTR  65          // LDS floats per staged row (odd -> conflict-free)
#define LSTR  24          // LDS halfs per LUT entry (48B, b128 banks <=2-way)
#define EBLK  2048        // encode blocks: 2048 * 2 tiles * 64 rows = 262144
#define ABLK  1024        // accum blocks: 1024 * 256 rows = 262144

typedef __attribute__((ext_vector_type(8))) _Float16 half8;
typedef __attribute__((ext_vector_type(4))) unsigned int u32x4;

__device__ __forceinline__ void scatter_tile(const float4* R, float* rows_s, int t) {
    #pragma unroll
    for (int j = 0; j < 16; ++j) {
        int f    = j * 64 + t;
        int row  = f >> 4;
        int colq = (f & 15) * 4;
        float* dst = &rows_s[row * RSTR + colq];
        dst[0] = R[j].x; dst[1] = R[j].y; dst[2] = R[j].z; dst[3] = R[j].w;
    }
}

// Encode one staged 64-row tile. All sv reads are independent broadcast LDS
// loads; the 4-level split walk is a cndmask tree (no dependent LDS chain).
__device__ __forceinline__ void encode_tile(
    const float* rows_s, const float* sv_s, const int* __restrict__ sd,
    int t, unsigned int& lo, unsigned int& hi)
{
    const float* rrow = &rows_s[t * RSTR];
    lo = 0; hi = 0;
    #pragma unroll
    for (int c = 0; c < 16; ++c) {
        const int sd0 = sd[c*4+0], sd1 = sd[c*4+1];
        const int sd2 = sd[c*4+2], sd3 = sd[c*4+3];
        float x0 = rrow[sd0];
        float x1 = rrow[sd1];
        float x2 = rrow[sd2];
        float x3 = rrow[sd3];

        const float* svc = &sv_s[c * 32];
        float  v1  = svc[0];                          // level 1 (g=0)
        float2 v2  = *(const float2*)(svc + 8);       // level 2, g in 0..1
        float4 v3  = *(const float4*)(svc + 16);      // level 3, g in 0..3
        float4 v4a = *(const float4*)(svc + 24);      // level 4, g in 0..3
        float4 v4b = *(const float4*)(svc + 28);      // level 4, g in 4..7

        bool b0 = x0 > v1;
        float v2s = b0 ? v2.y : v2.x;
        bool b1 = x1 > v2s;
        float v3hi = b1 ? v3.w : v3.z;
        float v3lo = b1 ? v3.y : v3.x;
        float v3s  = b0 ? v3hi : v3lo;
        bool b2 = x2 > v3s;
        float4 v4  = b0 ? v4b : v4a;
        float v4hi = b2 ? v4.w : v4.z;
        float v4lo = b2 ? v4.y : v4.x;
        float v4s  = b1 ? v4hi : v4lo;
        bool b3 = x3 > v4s;

        unsigned int g = ((((((unsigned)b0 << 1) | (unsigned)b1) << 1)
                           | (unsigned)b2) << 1) | (unsigned)b3;
        if (c < 8) lo |= g << (4 * c);
        else       hi |= g << (4 * (c - 8));
    }
}

__global__ __launch_bounds__(64) void encode_kernel(
    const float* __restrict__ A,      // [N][64]
    const float* __restrict__ B,      // [16][64]
    const float* __restrict__ P,      // [16][16][64]
    const int*   __restrict__ sd,     // [16][4]
    const float* __restrict__ sv,     // [16][4][8]
    _Float16* __restrict__ lutw,      // [256][16] f16 (d_ws)
    uint2* __restrict__ codes)        // [N] packed 16x4-bit (d_ws+8KB)
{
    __shared__ float rows_s[64 * RSTR];              // 16,640 B
    __shared__ __align__(16) float sv_s[512];        //  2,048 B
    const int t = threadIdx.x;

    // issue tile-0 A loads first (earliest HBM issue; 64 rows = 1024 float4)
    const float4* A4 = (const float4*)A;
    const long base0 = (long)blockIdx.x * (128 * DDIM / 4);   // 2 tiles/block
    float4 R0[16];
    #pragma unroll
    for (int j = 0; j < 16; ++j) R0[j] = A4[base0 + j * 64 + t];

    // stage split_vals (512 floats = 128 float4; 2 per thread)
    ((float4*)sv_s)[t]      = ((const float4*)sv)[t];
    ((float4*)sv_s)[t + 64] = ((const float4*)sv)[t + 64];

    // fused LUT build on first 16 blocks (independent; overlaps A-load wait)
    if (blockIdx.x < 16) {
        const int m = t & 15;
        const float4* Bp = (const float4*)(B + m * DDIM);
        float4 brow[16];
        #pragma unroll
        for (int q = 0; q < 16; ++q) brow[q] = Bp[q];
        #pragma unroll
        for (int i = 0; i < 4; ++i) {
            int o  = blockIdx.x * 256 + i * 64 + t;   // c*256 + k*16 + m
            int ck = o >> 4;
            const float4* Pp = (const float4*)(P + ck * DDIM);
            float dot = 0.f;
            #pragma unroll
            for (int q = 0; q < 16; ++q) {
                float4 p = Pp[q];
                dot += p.x * brow[q].x + p.y * brow[q].y
                     + p.z * brow[q].z + p.w * brow[q].w;
            }
            lutw[o] = (_Float16)dot;
        }
    }

    // tile 0: scatter (row stride 65: 2 lanes/bank = free), encode
    scatter_tile(R0, rows_s, t);
    __syncthreads();   // single wave: cheap lgkmcnt drain

    // prefetch tile 1 while tile 0 encodes (R1 latency hides under encode)
    float4 R1[16];
    #pragma unroll
    for (int j = 0; j < 16; ++j) R1[j] = A4[base0 + 1024 + j * 64 + t];

    unsigned int lo0, hi0;
    encode_tile(rows_s, sv_s, sd, t, lo0, hi0);
    codes[blockIdx.x * 128 + t] = make_uint2(lo0, hi0);

    __syncthreads();   // tile-0 LDS reads retired before overwrite
    scatter_tile(R1, rows_s, t);
    __syncthreads();

    unsigned int lo1, hi1;
    encode_tile(rows_s, sv_s, sd, t, lo1, hi1);
    codes[blockIdx.x * 128 + 64 + t] = make_uint2(lo1, hi1);
}

__global__ __launch_bounds__(256) void accum_kernel(
    const uint2* __restrict__ codes,  // [N]
    const _Float16* __restrict__ lutw,// [256][16] f16
    float* __restrict__ out)          // [16][N]
{
    __shared__ __align__(16) _Float16 lut_s[256 * LSTR];  // 12,288 B
    const int t = threadIdx.x;

    // issue code load first; its latency hides under the LUT staging below
    const int n = blockIdx.x * 256 + t;
    const uint2 code = codes[n];

    // stage LUT: one 32B entry per thread, padded stride 24 halfs
    {
        const u32x4* src = (const u32x4*)(lutw + t * 16);
        u32x4 q0 = src[0], q1 = src[1];
        *(u32x4*)(lut_s + t * LSTR)     = q0;
        *(u32x4*)(lut_s + t * LSTR + 8) = q1;
    }
    __syncthreads();

    half8 aE0 = {0,0,0,0,0,0,0,0}, aE1 = {0,0,0,0,0,0,0,0};
    half8 aO0 = {0,0,0,0,0,0,0,0}, aO1 = {0,0,0,0,0,0,0,0};

    #pragma unroll
    for (int c = 0; c < 8; ++c) {
        int g = (code.x >> (4 * c)) & 15;
        const _Float16* lp = lut_s + (c * 16 + g) * LSTR;
        half8 l0 = *(const half8*)(lp);
        half8 l1 = *(const half8*)(lp + 8);
        if (c & 1) { aO0 += l0; aO1 += l1; }
        else       { aE0 += l0; aE1 += l1; }
    }
    #pragma unroll
    for (int c = 8; c < 16; ++c) {
        int g = (code.y >> (4 * (c - 8))) & 15;
        const _Float16* lp = lut_s + (c * 16 + g) * LSTR;
        half8 l0 = *(const half8*)(lp);
        half8 l1 = *(const half8*)(lp + 8);
        if (c & 1) { aO0 += l0; aO1 += l1; }
        else       { aE0 += l0; aE1 += l1; }
    }

    #pragma unroll
    for (int m = 0; m < 8; ++m) {
        out[(long)m       * NROWS + n] = (float)aE0[m] + (float)aO0[m];
        out[(long)(m + 8) * NROWS + n] = (float)aE1[m] + (float)aO1[m];
    }
}

extern "C" void kernel_launch(void* const* d_in, const int* in_sizes, int n_in,
                              void* d_out, int out_size, void* d_ws, size_t ws_size,
                              hipStream_t stream) {
    const float* A  = (const float*)d_in[0];
    const float* B  = (const float*)d_in[1];
    const float* P  = (const float*)d_in[2];
    const int*   sd = (const int*)d_in[3];
    const float* sv = (const float*)d_in[4];
    float* out = (float*)d_out;

    _Float16* lutw = (_Float16*)d_ws;                 // 8 KB f16 LUT
    uint2*    codes = (uint2*)((char*)d_ws + 8192);   // 2 MB packed codes

    encode_kernel<<<dim3(EBLK), dim3(64), 0, stream>>>(A, B, P, sd, sv, lutw, codes);
    accum_kernel<<<dim3(ABLK), dim3(256), 0, stream>>>(codes, lutw, out);
}